// Round 1
// baseline (139.025 us; speedup 1.0000x reference)
//
#include <hip/hip_runtime.h>
#include <hip/hip_bf16.h>

// out[b,k] = sum_{i,j} x[b,i] * W[k,i,j] * x[b,j]
// Symmetric reduction: out[b,k] = sum_{p=(i<=j)} Q[p,k] * x_i*x_j,
//   Q[p,k] = W[k,i,j] + W[k,j,i]  (i<j),  W[k,i,i]  (i==j).
// GEMM: P (B x 136) @ Q (136 x 16), K padded to 160 = 5 x mfma_f32_16x16x32_bf16.
// Products computed in fp32, rounded once to bf16. Memory-bound target: 128 MB @ ~6.3 TB/s.

typedef __attribute__((ext_vector_type(8)))  short  short8;
typedef __attribute__((ext_vector_type(8)))  __bf16 bf16x8;
typedef __attribute__((ext_vector_type(4)))  float  floatx4;

#define DEV static __device__ __forceinline__

// ---- compile-time pair index decode: p -> (i,j), i<=j, row-major upper triangle ----
constexpr int pair_base(int i) { return i * 16 - (i * (i - 1)) / 2; }   // p of (i,i)
constexpr int pi_of(int p) { int i = 0; while (pair_base(i + 1) <= p) ++i; return i; }
constexpr int pj_of(int p) { return pi_of(p) + (p - pair_base(pi_of(p))); }

template <int P>
DEV float pval(const float* xv) {
    if constexpr (P >= 136) {
        return 0.f;                       // K padding 136..159
    } else {
        constexpr int I = pi_of(P);
        constexpr int J = pj_of(P);
        return xv[I] * xv[J];             // constant indices -> stays in registers
    }
}

template <int BASE>
DEV short8 make_afrag(const float* xv) {
    union { short8 s; __hip_bfloat162 h[4]; } u;
    u.h[0] = __float22bfloat162_rn(make_float2(pval<BASE + 0>(xv), pval<BASE + 1>(xv)));
    u.h[1] = __float22bfloat162_rn(make_float2(pval<BASE + 2>(xv), pval<BASE + 3>(xv)));
    u.h[2] = __float22bfloat162_rn(make_float2(pval<BASE + 4>(xv), pval<BASE + 5>(xv)));
    u.h[3] = __float22bfloat162_rn(make_float2(pval<BASE + 6>(xv), pval<BASE + 7>(xv)));
    return u.s;
}

// Lane-quad H holds A-frag k-slots {32*s + 8*H + j}. B-frags use the identical
// slot->pair mapping, so any internal k permutation cancels (A/B slots pair up).
template <int H>
DEV void build_afrags(const float* xv, short8& a0, short8& a1, short8& a2,
                      short8& a3, short8& a4) {
    a0 = make_afrag<0 * 32 + H * 8>(xv);
    a1 = make_afrag<1 * 32 + H * 8>(xv);
    a2 = make_afrag<2 * 32 + H * 8>(xv);
    a3 = make_afrag<3 * 32 + H * 8>(xv);
    a4 = make_afrag<4 * 32 + H * 8>(xv);
}

DEV floatx4 mfma_bf16(short8 a, short8 b, floatx4 c) {
    return __builtin_amdgcn_mfma_f32_16x16x32_bf16(
        __builtin_bit_cast(bf16x8, a), __builtin_bit_cast(bf16x8, b), c, 0, 0, 0);
}

__global__ __launch_bounds__(256, 4)
void bilinear16_kernel(const float* __restrict__ x, const float* __restrict__ W,
                       float* __restrict__ out, int ntiles) {
    // ---- per-block setup: Q^T in LDS, [channel n][pair p], bf16 ----
    __shared__ __align__(16) short Qt[16][160];
    const int tid = threadIdx.x;
    for (int idx = tid; idx < 16 * 160; idx += 256) {
        const int n = idx / 160;
        const int p = idx - n * 160;
        float q = 0.f;
        if (p < 136) {
            int i = 0, rem = p;
            while (rem >= 16 - i) { rem -= 16 - i; ++i; }   // runtime decode (setup only)
            const int j = i + rem;
            q = W[n * 256 + i * 16 + j];
            if (i != j) q += W[n * 256 + j * 16 + i];
        }
        __hip_bfloat16 h = __float2bfloat16(q);
        Qt[n][p] = *reinterpret_cast<short*>(&h);
    }
    __syncthreads();

    const int lane = tid & 63;
    const int n    = lane & 15;   // A row m / B col n / C col
    const int quad = lane >> 4;

    // B-frags live in registers for the whole loop (20 VGPRs).
    const short8 b0 = *reinterpret_cast<const short8*>(&Qt[n][0 * 32 + quad * 8]);
    const short8 b1 = *reinterpret_cast<const short8*>(&Qt[n][1 * 32 + quad * 8]);
    const short8 b2 = *reinterpret_cast<const short8*>(&Qt[n][2 * 32 + quad * 8]);
    const short8 b3 = *reinterpret_cast<const short8*>(&Qt[n][3 * 32 + quad * 8]);
    const short8 b4 = *reinterpret_cast<const short8*>(&Qt[n][4 * 32 + quad * 8]);

    const int waveId = blockIdx.x * 4 + (tid >> 6);
    const int nwaves = gridDim.x * 4;

    for (int t = waveId; t < ntiles; t += nwaves) {
        // Each lane loads its tile row (4 lanes share a row; L1 absorbs the 4x).
        const float4* xr = reinterpret_cast<const float4*>(x + (size_t)(t * 16 + n) * 16);
        const float4 c0 = xr[0], c1 = xr[1], c2 = xr[2], c3 = xr[3];
        float xv[16] = {c0.x, c0.y, c0.z, c0.w, c1.x, c1.y, c1.z, c1.w,
                        c2.x, c2.y, c2.z, c2.w, c3.x, c3.y, c3.z, c3.w};

        short8 a0, a1, a2, a3, a4;
        if      (quad == 0) build_afrags<0>(xv, a0, a1, a2, a3, a4);
        else if (quad == 1) build_afrags<1>(xv, a0, a1, a2, a3, a4);
        else if (quad == 2) build_afrags<2>(xv, a0, a1, a2, a3, a4);
        else                build_afrags<3>(xv, a0, a1, a2, a3, a4);

        floatx4 acc = {0.f, 0.f, 0.f, 0.f};
        acc = mfma_bf16(a0, b0, acc);
        acc = mfma_bf16(a1, b1, acc);
        acc = mfma_bf16(a2, b2, acc);
        acc = mfma_bf16(a3, b3, acc);
        acc = mfma_bf16(a4, b4, acc);

        // C/D layout: col = lane&15, row = quad*4 + reg  [m89-verified]
        float* orow = out + (size_t)(t * 16 + quad * 4) * 16 + n;
        orow[0]  = acc[0];
        orow[16] = acc[1];
        orow[32] = acc[2];
        orow[48] = acc[3];
    }
}

extern "C" void kernel_launch(void* const* d_in, const int* in_sizes, int n_in,
                              void* d_out, int out_size, void* d_ws, size_t ws_size,
                              hipStream_t stream) {
    const float* x = (const float*)d_in[0];
    const float* W = (const float*)d_in[1];
    float* out = (float*)d_out;
    const int Bn = in_sizes[0] / 16;   // 1048576
    const int ntiles = Bn >> 4;        // 65536 (B is a multiple of 16)
    bilinear16_kernel<<<1024, 256, 0, stream>>>(x, W, out, ntiles);
}

// Round 2
// 127.169 us; speedup vs baseline: 1.0932x; 1.0932x over previous
//
#include <hip/hip_runtime.h>
#include <hip/hip_bf16.h>

// out[b,k] = sum_{i,j} x[b,i] * W[k,i,j] * x[b,j]
// GEMM P (B x 136sym-pairs) @ Q (136 x 16), K padded to 160 = 5 x mfma_f32_16x16x32_bf16.
//
// Divergence-free A-frag build: lane quad q loads its row ROTATED by 4q
// (chunk t <- raw chunk (t+q)&3), and the pair->K-slot permutation is chosen
// so slot class c (= 8s+j) at quad q holds pair ((alpha_c+4q)%16, (beta_c+4q)%16).
// Then every lane computes xv[alpha_c]*xv[beta_c] with compile-time constant
// indices -- identical code across all 64 lanes, no exec-mask serialization.
//
// Class table (c = 0..39):
//   c <  32: d=c>>2 (0..7), i0=c&3 : (alpha,beta) = (i0, i0+d), weight 1
//   c < 36 : i0=c-32        : (alpha,beta) = (i0, i0+8), weight 0.5  (orbit size 2
//            => each d=8 pair appears in two K slots, so Q is halved)
//   else   : dead padding, weight 0
// beta <= 11 => only rotated chunks 0..2 needed (12 floats/lane, not 16).

typedef __attribute__((ext_vector_type(8)))  short  short8;
typedef __attribute__((ext_vector_type(8)))  __bf16 bf16x8;
typedef __attribute__((ext_vector_type(4)))  float  floatx4;

#define DEV static __device__ __forceinline__

constexpr int  alpha_of(int c) { return (c < 32) ? (c & 3) : (c - 32); }
constexpr int  beta_of(int c)  { return (c < 32) ? ((c & 3) + (c >> 2)) : (c - 32 + 8); }
constexpr bool live_of(int c)  { return c < 36; }

template <int C>
DEV float pval(const float* xv) {
    if constexpr (!live_of(C)) return 0.f;
    else return xv[alpha_of(C)] * xv[beta_of(C)];   // constant indices, uniform code
}

template <int S>   // frag S covers classes c = 8S .. 8S+7
DEV short8 make_afrag(const float* xv) {
    union { short8 s; __hip_bfloat162 h[4]; } u;
    u.h[0] = __float22bfloat162_rn(make_float2(pval<8 * S + 0>(xv), pval<8 * S + 1>(xv)));
    u.h[1] = __float22bfloat162_rn(make_float2(pval<8 * S + 2>(xv), pval<8 * S + 3>(xv)));
    u.h[2] = __float22bfloat162_rn(make_float2(pval<8 * S + 4>(xv), pval<8 * S + 5>(xv)));
    u.h[3] = __float22bfloat162_rn(make_float2(pval<8 * S + 6>(xv), pval<8 * S + 7>(xv)));
    return u.s;
}

DEV floatx4 mfma_bf16(short8 a, short8 b, floatx4 c) {
    return __builtin_amdgcn_mfma_f32_16x16x32_bf16(
        __builtin_bit_cast(bf16x8, a), __builtin_bit_cast(bf16x8, b), c, 0, 0, 0);
}

__global__ __launch_bounds__(256, 4)
void bilinear16_kernel(const float* __restrict__ x, const float* __restrict__ W,
                       float* __restrict__ out, int ntiles) {
    // ---- per-block setup: Qt[n][k] bf16, k-slot -> rotated pair, weight-adjusted ----
    __shared__ __align__(16) short Qt[16][160];
    const int tid = threadIdx.x;
    for (int idx = tid; idx < 16 * 160; idx += 256) {
        const int n = idx / 160;
        const int k = idx - n * 160;
        const int s = k >> 5, q = (k >> 3) & 3, j = k & 7;
        const int c = 8 * s + j;
        float qv = 0.f;
        if (c < 36) {
            const int a = (c < 32) ? (c & 3) : (c - 32);
            const int b = (c < 32) ? ((c & 3) + (c >> 2)) : (c - 32 + 8);
            const float w = (c < 32) ? 1.0f : 0.5f;
            const int I = (a + 4 * q) & 15, J = (b + 4 * q) & 15;
            qv = (I == J) ? W[n * 256 + I * 16 + I]
                          : w * (W[n * 256 + I * 16 + J] + W[n * 256 + J * 16 + I]);
        }
        __hip_bfloat16 h = __float2bfloat16(qv);
        Qt[n][k] = *reinterpret_cast<short*>(&h);
    }
    __syncthreads();

    const int lane = tid & 63;
    const int n    = lane & 15;   // A row m / B col n / C col
    const int q    = lane >> 4;   // quad -> data rotation only, never a branch

    // B-frags in registers for the whole loop (20 VGPRs).
    const short8 b0 = *reinterpret_cast<const short8*>(&Qt[n][0 * 32 + q * 8]);
    const short8 b1 = *reinterpret_cast<const short8*>(&Qt[n][1 * 32 + q * 8]);
    const short8 b2 = *reinterpret_cast<const short8*>(&Qt[n][2 * 32 + q * 8]);
    const short8 b3 = *reinterpret_cast<const short8*>(&Qt[n][3 * 32 + q * 8]);
    const short8 b4 = *reinterpret_cast<const short8*>(&Qt[n][4 * 32 + q * 8]);

    const int waveId = blockIdx.x * 4 + (tid >> 6);
    const int nwaves = gridDim.x * 4;

    for (int t = waveId; t < ntiles; t += nwaves) {
        // Rotated row load: rotated chunk u = raw chunk (u+q)&3; chunks 0..2 suffice.
        // Each load inst's 64 lane addresses tile the full 1KB x-tile (coalesced).
        const float4* xr = reinterpret_cast<const float4*>(x + (size_t)(t * 16 + n) * 16);
        const float4 c0 = xr[q];
        const float4 c1 = xr[(q + 1) & 3];
        const float4 c2 = xr[(q + 2) & 3];
        const float xv[12] = {c0.x, c0.y, c0.z, c0.w,
                              c1.x, c1.y, c1.z, c1.w,
                              c2.x, c2.y, c2.z, c2.w};

        const short8 a0 = make_afrag<0>(xv);
        const short8 a1 = make_afrag<1>(xv);
        const short8 a2 = make_afrag<2>(xv);
        const short8 a3 = make_afrag<3>(xv);
        const short8 a4 = make_afrag<4>(xv);

        floatx4 acc = {0.f, 0.f, 0.f, 0.f};
        acc = mfma_bf16(a0, b0, acc);
        acc = mfma_bf16(a1, b1, acc);
        acc = mfma_bf16(a2, b2, acc);
        acc = mfma_bf16(a3, b3, acc);
        acc = mfma_bf16(a4, b4, acc);

        // C/D layout: col = lane&15, row = quad*4 + reg  [m89-verified]
        float* orow = out + (size_t)(t * 16 + q * 4) * 16 + n;
        orow[0]  = acc[0];
        orow[16] = acc[1];
        orow[32] = acc[2];
        orow[48] = acc[3];
    }
}

extern "C" void kernel_launch(void* const* d_in, const int* in_sizes, int n_in,
                              void* d_out, int out_size, void* d_ws, size_t ws_size,
                              hipStream_t stream) {
    const float* x = (const float*)d_in[0];
    const float* W = (const float*)d_in[1];
    float* out = (float*)d_out;
    const int Bn = in_sizes[0] / 16;   // 1048576
    const int ntiles = Bn >> 4;        // 65536
    bilinear16_kernel<<<2048, 256, 0, stream>>>(x, W, out, ntiles);
}